// Round 8
// baseline (421.639 us; speedup 1.0000x reference)
//
#include <hip/hip_runtime.h>
#include <math.h>

// ---------------------------------------------------------------------------
// TersoffAttention (R7 = R6 + merge-condition fix): CSR sort + fused segment
// kernel with 8-lane groups.
//   Wave = segment; 8 groups x 8 lanes; each pass processes 8 triplets
//   (one per group, 8 channels per lane):
//     - dot-reduce = 3 shfl_xor per 8 triplets (was 6 per 1 triplet in R5)
//     - cos(k*theta) via Chebyshev recurrence z_{k+1}=2cos(th)z_k - z_{k-1},
//       multiplier from the already-computed cosj (no trig) -> 2 seed v_cos
//     - per-group online softmax (m, den, acc[8])
//   R7 FIX: triplet->group distribution is INTERLEAVED (group g takes triplet
//   j8+g), so the cross-group merge is required whenever len > 1, not len > 8.
//   R6's "if (len > 8)" dropped groups 1..7 for short segments (absmax 6.59).
//   Inactive groups (m=-inf, p=1 garbage) are zeroed by the merge's s2=0.
// Kernels: memsetAsync(rowptr) -> init -> hist -> scan(1 block) -> scatter
//          -> fused
// ---------------------------------------------------------------------------

#define LOG2E 1.4426950408889634f

__global__ void ta_init(const float* __restrict__ r,
                        float4* __restrict__ rnorm4,
                        int E) {
    int i = blockIdx.x * blockDim.x + threadIdx.x;
    if (i < E) {
        float rx = r[i * 3 + 0], ry = r[i * 3 + 1], rz = r[i * 3 + 2];
        float inv = rsqrtf(rx * rx + ry * ry + rz * rz);
        rnorm4[i] = make_float4(rx * inv, ry * inv, rz * inv, 0.f);
    }
}

__global__ void ta_hist(const int* __restrict__ t_dst,
                        int* __restrict__ rowptr, int T) {
    int t = blockIdx.x * blockDim.x + threadIdx.x;
    if (t < T) atomicAdd(&rowptr[t_dst[t]], 1);
}

// single-block exclusive scan over E counters (1024 threads, serial chunks)
__global__ void ta_scan(int* __restrict__ rowptr, int E) {
    __shared__ int sm[1024];
    const int tid = threadIdx.x;
    const int per = (E + 1023) >> 10;
    int lo = tid * per, hi = lo + per;
    if (hi > E) hi = E;
    int sum = 0;
    for (int i = lo; i < hi; ++i) sum += rowptr[i];
    sm[tid] = sum;
    __syncthreads();
    int x = sum;
    for (int o = 1; o < 1024; o <<= 1) {
        int y = (tid >= o) ? sm[tid - o] : 0;
        __syncthreads();
        x += y;
        sm[tid] = x;
        __syncthreads();
    }
    int run = x - sum;                     // exclusive prefix of this chunk
    for (int i = lo; i < hi; ++i) { int v = rowptr[i]; rowptr[i] = run; run += v; }
}

// scatter: ssorted[pos] = t_src[t]; afterwards rowptr[e] == end-of-segment(e)
__global__ void ta_scatter(const int* __restrict__ t_dst,
                           const int* __restrict__ t_src,
                           int* __restrict__ rowptr,
                           int* __restrict__ ssorted, int T) {
    int t = blockIdx.x * blockDim.x + threadIdx.x;
    if (t < T) {
        int pos = atomicAdd(&rowptr[t_dst[t]], 1);
        ssorted[pos] = t_src[t];
    }
}

// fused: one wave per dst edge e. Phase A (lane=triplet): acos batch of 64.
// Phase B: 8 groups x 8 lanes, 8 triplets/pass, 8 channels/lane.
__global__ void ta_fused(const float* __restrict__ xij,
                         const float* __restrict__ attn,
                         const float4* __restrict__ rnorm4,
                         const int* __restrict__ ssorted,
                         const int* __restrict__ segend,
                         float* __restrict__ ft, int E) {
    const int lane = threadIdx.x & 63;
    const int waveId = blockIdx.x * (blockDim.x >> 6) + (threadIdx.x >> 6);
    if (waveId >= E) return;
    const int e = waveId;
    const int g   = lane >> 3;          // group 0..7 (triplet slot within pass)
    const int sub = lane & 7;           // lane within group
    const int c0  = sub * 8;            // first channel of this lane's octet
    const float fc0 = (float)c0;

    int end = segend[e];
    int start = (e == 0) ? 0 : segend[e - 1];
    int len = end - start;

    float xd[8], at[8];
    const float* xdp = xij + (size_t)e * 64 + c0;
    *(float4*)&xd[0] = *(const float4*)(xdp);
    *(float4*)&xd[4] = *(const float4*)(xdp + 4);
    *(float4*)&at[0] = *(const float4*)(attn + c0);
    *(float4*)&at[4] = *(const float4*)(attn + c0 + 4);
    const float4 rd = rnorm4[e];

    float m = -3.402823466e38f, den = 0.f;
    float acc[8] = {0, 0, 0, 0, 0, 0, 0, 0};

    for (int chunk = start; chunk < end; chunk += 64) {
        int cl = end - chunk; if (cl > 64) cl = 64;
        // ---- phase A: lane = triplet slot (full-width acos batch) ----
        int idx = chunk + lane; if (idx >= end) idx = end - 1;
        int sv = ssorted[idx];
        float4 rs = rnorm4[sv];
        float cosj = rs.x * rd.x + rs.y * rd.y + rs.z * rd.z;
        cosj = fminf(fmaxf(cosj, -1.0f + 1e-6f), 1.0f - 1e-6f);
        float th2p = acosf(cosj) * 0.15915493667125702f;   // theta/(2pi)

        // ---- phase B: 8 triplets per pass (group g takes triplet j8+g) ----
        for (int j8 = 0; j8 < cl; j8 += 8) {
            int jj = j8 + g;
            bool active = (jj < cl);
            int jc = active ? jj : 0;
            float th = __shfl(th2p, jc, 64);   // theta/(2pi), group-uniform
            float tc = __shfl(cosj, jc, 64);   // cos(theta): Chebyshev mult/2
            int   s  = __shfl(sv,   jc, 64);

            const float* xsp = xij + (size_t)s * 64 + c0;
            float xs[8];
            *(float4*)&xs[0] = *(const float4*)(xsp);
            *(float4*)&xs[4] = *(const float4*)(xsp + 4);

            // Chebyshev seeds: cos(c0*th), cos((c0+1)*th); then recurrence
            float r0 = th * fc0;
            float z0 = __builtin_amdgcn_cosf(r0 - floorf(r0));
            float r1 = r0 + th;
            float z1 = __builtin_amdgcn_cosf(r1 - floorf(r1));
            float twoc = 2.0f * tc;

            float part = 0.f;
            float zkm1 = z0, zk = z1;
            #pragma unroll
            for (int k = 0; k < 8; ++k) {
                float z = (k == 0) ? z0 : zk;
                float v = z + xs[k] + xd[k];
                float ez = __builtin_amdgcn_exp2f(-v * LOG2E);
                float sl = v * __builtin_amdgcn_rcpf(1.0f + ez);   // silu
                part = fmaf(sl, at[k], part);
                if (k > 0) {                       // advance recurrence
                    float zn = fmaf(twoc, zk, -zkm1);
                    zkm1 = zk; zk = zn;
                }
            }
            // dot-reduce within the 8-lane group
            part += __shfl_xor(part, 1, 64);
            part += __shfl_xor(part, 2, 64);
            part += __shfl_xor(part, 4, 64);
            float contrib = active ? part : -3.402823466e38f;
            // per-group online softmax
            float mn = fmaxf(m, contrib);
            float scale = __builtin_amdgcn_exp2f((m - mn) * LOG2E);
            float p     = __builtin_amdgcn_exp2f((contrib - mn) * LOG2E);
            den = den * scale + p;
            #pragma unroll
            for (int k = 0; k < 8; ++k) acc[k] = fmaf(p, xs[k], acc[k] * scale);
            m = mn;
        }
    }

    // merge the 8 groups: required whenever more than one triplet exists,
    // because distribution is interleaved (group g holds triplets j8+g).
    if (len > 1) {
        #pragma unroll
        for (int off = 8; off < 64; off <<= 1) {
            float m2 = __shfl_xor(m, off, 64);
            float d2 = __shfl_xor(den, off, 64);
            float mn = fmaxf(m, m2);
            float s1 = __builtin_amdgcn_exp2f((m - mn) * LOG2E);
            float s2 = __builtin_amdgcn_exp2f((m2 - mn) * LOG2E);
            den = den * s1 + d2 * s2;
            #pragma unroll
            for (int k = 0; k < 8; ++k) {
                float a2 = __shfl_xor(acc[k], off, 64);
                acc[k] = acc[k] * s1 + a2 * s2;
            }
            m = mn;
        }
    }

    float rden = (len > 0) ? __builtin_amdgcn_rcpf(den) : 0.f;
    if (lane < 8) {                       // lanes 0..7 = group 0, sub = lane
        float out[8];
        #pragma unroll
        for (int k = 0; k < 8; ++k) out[k] = acc[k] * rden;
        float* fo = ft + (size_t)e * 64 + lane * 8;
        *(float4*)(fo)     = *(float4*)&out[0];
        *(float4*)(fo + 4) = *(float4*)&out[4];
    }
}

extern "C" void kernel_launch(void* const* d_in, const int* in_sizes, int n_in,
                              void* d_out, int out_size, void* d_ws, size_t ws_size,
                              hipStream_t stream) {
    const float* xij   = (const float*)d_in[0];
    const float* r     = (const float*)d_in[1];
    const float* attn  = (const float*)d_in[2];
    const int*   t_src = (const int*)d_in[3];
    const int*   t_dst = (const int*)d_in[4];
    float* ft = (float*)d_out;

    const int E = in_sizes[1] / 3;   // r is [E,3]
    const int T = in_sizes[3];       // t_src is [T]

    // workspace layout (~6 MB for E=100k, T=1M)
    char* ws = (char*)d_ws;
    float4* rnorm4  = (float4*)ws;                                   // E*16 B
    int*    ssorted = (int*)(ws + (size_t)E * 16);                   // T*4 B
    int*    rowptr  = (int*)((char*)ssorted + (size_t)T * 4);        // E*4 B

    hipMemsetAsync(rowptr, 0, (size_t)E * 4, stream);
    ta_init<<<(E + 255) / 256, 256, 0, stream>>>(r, rnorm4, E);
    ta_hist<<<(T + 255) / 256, 256, 0, stream>>>(t_dst, rowptr, T);
    ta_scan<<<1, 1024, 0, stream>>>(rowptr, E);
    ta_scatter<<<(T + 255) / 256, 256, 0, stream>>>(t_dst, t_src, rowptr, ssorted, T);
    ta_fused<<<(E + 3) / 4, 256, 0, stream>>>(xij, attn, rnorm4, ssorted, rowptr, ft, E);
}

// Round 9
// 267.691 us; speedup vs baseline: 1.5751x; 1.5751x over previous
//
#include <hip/hip_runtime.h>
#include <math.h>

// ---------------------------------------------------------------------------
// TersoffAttention (R8 = R7 + scan revert): CSR sort + fused segment kernel
// with 8-lane groups.
//   R7's single-block ta_scan was 162us at 0.16% occupancy (serial loops over
//   E/1024 elements). Revert to the R5 3-kernel scan (per-block scan + single
//   block over <=512 block sums + add-offsets), which never showed in top-5.
//   Everything else identical to R7 (passed, absmax 0.0156).
// Kernels: memsetAsync(rowptr) -> init -> hist -> scan1/scan2/scan3
//          -> scatter -> fused
// ---------------------------------------------------------------------------

#define LOG2E 1.4426950408889634f
#define SCAN_B 256

__global__ void ta_init(const float* __restrict__ r,
                        float4* __restrict__ rnorm4,
                        int E) {
    int i = blockIdx.x * blockDim.x + threadIdx.x;
    if (i < E) {
        float rx = r[i * 3 + 0], ry = r[i * 3 + 1], rz = r[i * 3 + 2];
        float inv = rsqrtf(rx * rx + ry * ry + rz * rz);
        rnorm4[i] = make_float4(rx * inv, ry * inv, rz * inv, 0.f);
    }
}

__global__ void ta_hist(const int* __restrict__ t_dst,
                        int* __restrict__ rowptr, int T) {
    int t = blockIdx.x * blockDim.x + threadIdx.x;
    if (t < T) atomicAdd(&rowptr[t_dst[t]], 1);
}

// scan phase 1: per-block exclusive scan + block totals
__global__ void ta_scan1(int* __restrict__ rowptr, int* __restrict__ bsum, int E) {
    __shared__ int sm[SCAN_B];
    int i = blockIdx.x * SCAN_B + threadIdx.x;
    int v = (i < E) ? rowptr[i] : 0;
    sm[threadIdx.x] = v;
    __syncthreads();
    int x = v;
    for (int o = 1; o < SCAN_B; o <<= 1) {
        int y = (threadIdx.x >= (unsigned)o) ? sm[threadIdx.x - o] : 0;
        __syncthreads();
        x += y;
        sm[threadIdx.x] = x;
        __syncthreads();
    }
    if (i < E) rowptr[i] = x - v;
    if (threadIdx.x == SCAN_B - 1) bsum[blockIdx.x] = x;
}

// scan phase 2: single-block exclusive scan of block totals (n <= 512)
__global__ void ta_scan2(int* __restrict__ bsum, int n) {
    __shared__ int sm[512];
    int tid = threadIdx.x;
    int v = (tid < n) ? bsum[tid] : 0;
    sm[tid] = v;
    __syncthreads();
    int x = v;
    for (int o = 1; o < 512; o <<= 1) {
        int y = (tid >= o) ? sm[tid - o] : 0;
        __syncthreads();
        x += y;
        sm[tid] = x;
        __syncthreads();
    }
    if (tid < n) bsum[tid] = x - v;
}

// scan phase 3: add scanned block offsets
__global__ void ta_scan3(int* __restrict__ rowptr, const int* __restrict__ bsum, int E) {
    int i = blockIdx.x * blockDim.x + threadIdx.x;
    if (i < E) rowptr[i] += bsum[i >> 8];         // 256 == SCAN_B
}

// scatter: ssorted[pos] = t_src[t]; afterwards rowptr[e] == end-of-segment(e)
__global__ void ta_scatter(const int* __restrict__ t_dst,
                           const int* __restrict__ t_src,
                           int* __restrict__ rowptr,
                           int* __restrict__ ssorted, int T) {
    int t = blockIdx.x * blockDim.x + threadIdx.x;
    if (t < T) {
        int pos = atomicAdd(&rowptr[t_dst[t]], 1);
        ssorted[pos] = t_src[t];
    }
}

// fused: one wave per dst edge e. Phase A (lane=triplet): acos batch of 64.
// Phase B: 8 groups x 8 lanes, 8 triplets/pass, 8 channels/lane.
__global__ void ta_fused(const float* __restrict__ xij,
                         const float* __restrict__ attn,
                         const float4* __restrict__ rnorm4,
                         const int* __restrict__ ssorted,
                         const int* __restrict__ segend,
                         float* __restrict__ ft, int E) {
    const int lane = threadIdx.x & 63;
    const int waveId = blockIdx.x * (blockDim.x >> 6) + (threadIdx.x >> 6);
    if (waveId >= E) return;
    const int e = waveId;
    const int g   = lane >> 3;          // group 0..7 (triplet slot within pass)
    const int sub = lane & 7;           // lane within group
    const int c0  = sub * 8;            // first channel of this lane's octet
    const float fc0 = (float)c0;

    int end = segend[e];
    int start = (e == 0) ? 0 : segend[e - 1];
    int len = end - start;

    float xd[8], at[8];
    const float* xdp = xij + (size_t)e * 64 + c0;
    *(float4*)&xd[0] = *(const float4*)(xdp);
    *(float4*)&xd[4] = *(const float4*)(xdp + 4);
    *(float4*)&at[0] = *(const float4*)(attn + c0);
    *(float4*)&at[4] = *(const float4*)(attn + c0 + 4);
    const float4 rd = rnorm4[e];

    float m = -3.402823466e38f, den = 0.f;
    float acc[8] = {0, 0, 0, 0, 0, 0, 0, 0};

    for (int chunk = start; chunk < end; chunk += 64) {
        int cl = end - chunk; if (cl > 64) cl = 64;
        // ---- phase A: lane = triplet slot (full-width acos batch) ----
        int idx = chunk + lane; if (idx >= end) idx = end - 1;
        int sv = ssorted[idx];
        float4 rs = rnorm4[sv];
        float cosj = rs.x * rd.x + rs.y * rd.y + rs.z * rd.z;
        cosj = fminf(fmaxf(cosj, -1.0f + 1e-6f), 1.0f - 1e-6f);
        float th2p = acosf(cosj) * 0.15915493667125702f;   // theta/(2pi)

        // ---- phase B: 8 triplets per pass (group g takes triplet j8+g) ----
        for (int j8 = 0; j8 < cl; j8 += 8) {
            int jj = j8 + g;
            bool active = (jj < cl);
            int jc = active ? jj : 0;
            float th = __shfl(th2p, jc, 64);   // theta/(2pi), group-uniform
            float tc = __shfl(cosj, jc, 64);   // cos(theta): Chebyshev mult/2
            int   s  = __shfl(sv,   jc, 64);

            const float* xsp = xij + (size_t)s * 64 + c0;
            float xs[8];
            *(float4*)&xs[0] = *(const float4*)(xsp);
            *(float4*)&xs[4] = *(const float4*)(xsp + 4);

            // Chebyshev seeds: cos(c0*th), cos((c0+1)*th); then recurrence
            float r0 = th * fc0;
            float z0 = __builtin_amdgcn_cosf(r0 - floorf(r0));
            float r1 = r0 + th;
            float z1 = __builtin_amdgcn_cosf(r1 - floorf(r1));
            float twoc = 2.0f * tc;

            float part = 0.f;
            float zkm1 = z0, zk = z1;
            #pragma unroll
            for (int k = 0; k < 8; ++k) {
                float z = (k == 0) ? z0 : zk;
                float v = z + xs[k] + xd[k];
                float ez = __builtin_amdgcn_exp2f(-v * LOG2E);
                float sl = v * __builtin_amdgcn_rcpf(1.0f + ez);   // silu
                part = fmaf(sl, at[k], part);
                if (k > 0) {                       // advance recurrence
                    float zn = fmaf(twoc, zk, -zkm1);
                    zkm1 = zk; zk = zn;
                }
            }
            // dot-reduce within the 8-lane group
            part += __shfl_xor(part, 1, 64);
            part += __shfl_xor(part, 2, 64);
            part += __shfl_xor(part, 4, 64);
            float contrib = active ? part : -3.402823466e38f;
            // per-group online softmax
            float mn = fmaxf(m, contrib);
            float scale = __builtin_amdgcn_exp2f((m - mn) * LOG2E);
            float p     = __builtin_amdgcn_exp2f((contrib - mn) * LOG2E);
            den = den * scale + p;
            #pragma unroll
            for (int k = 0; k < 8; ++k) acc[k] = fmaf(p, xs[k], acc[k] * scale);
            m = mn;
        }
    }

    // merge the 8 groups: required whenever len > 1 (interleaved distribution)
    if (len > 1) {
        #pragma unroll
        for (int off = 8; off < 64; off <<= 1) {
            float m2 = __shfl_xor(m, off, 64);
            float d2 = __shfl_xor(den, off, 64);
            float mn = fmaxf(m, m2);
            float s1 = __builtin_amdgcn_exp2f((m - mn) * LOG2E);
            float s2 = __builtin_amdgcn_exp2f((m2 - mn) * LOG2E);
            den = den * s1 + d2 * s2;
            #pragma unroll
            for (int k = 0; k < 8; ++k) {
                float a2 = __shfl_xor(acc[k], off, 64);
                acc[k] = acc[k] * s1 + a2 * s2;
            }
            m = mn;
        }
    }

    float rden = (len > 0) ? __builtin_amdgcn_rcpf(den) : 0.f;
    if (lane < 8) {                       // lanes 0..7 = group 0, sub = lane
        float out[8];
        #pragma unroll
        for (int k = 0; k < 8; ++k) out[k] = acc[k] * rden;
        float* fo = ft + (size_t)e * 64 + lane * 8;
        *(float4*)(fo)     = *(float4*)&out[0];
        *(float4*)(fo + 4) = *(float4*)&out[4];
    }
}

extern "C" void kernel_launch(void* const* d_in, const int* in_sizes, int n_in,
                              void* d_out, int out_size, void* d_ws, size_t ws_size,
                              hipStream_t stream) {
    const float* xij   = (const float*)d_in[0];
    const float* r     = (const float*)d_in[1];
    const float* attn  = (const float*)d_in[2];
    const int*   t_src = (const int*)d_in[3];
    const int*   t_dst = (const int*)d_in[4];
    float* ft = (float*)d_out;

    const int E = in_sizes[1] / 3;   // r is [E,3]
    const int T = in_sizes[3];       // t_src is [T]

    // workspace layout (~6 MB for E=100k, T=1M)
    char* ws = (char*)d_ws;
    float4* rnorm4  = (float4*)ws;                                   // E*16 B
    int*    ssorted = (int*)(ws + (size_t)E * 16);                   // T*4 B
    int*    rowptr  = (int*)((char*)ssorted + (size_t)T * 4);        // E*4 B
    int*    bsum    = (int*)((char*)rowptr + (size_t)E * 4);         // <=512*4 B

    const int nScanBlocks = (E + SCAN_B - 1) / SCAN_B;   // 391 for E=100k

    hipMemsetAsync(rowptr, 0, (size_t)E * 4, stream);
    ta_init<<<(E + 255) / 256, 256, 0, stream>>>(r, rnorm4, E);
    ta_hist<<<(T + 255) / 256, 256, 0, stream>>>(t_dst, rowptr, T);
    ta_scan1<<<nScanBlocks, SCAN_B, 0, stream>>>(rowptr, bsum, E);
    ta_scan2<<<1, 512, 0, stream>>>(bsum, nScanBlocks);
    ta_scan3<<<nScanBlocks, SCAN_B, 0, stream>>>(rowptr, bsum, E);
    ta_scatter<<<(T + 255) / 256, 256, 0, stream>>>(t_dst, t_src, rowptr, ssorted, T);
    ta_fused<<<(E + 3) / 4, 256, 0, stream>>>(xij, attn, rnorm4, ssorted, rowptr, ft, E);
}